// Round 7
// baseline (156.496 us; speedup 1.0000x reference)
//
#include <hip/hip_runtime.h>
#include <hip/hip_bf16.h>

// ---------------------------------------------------------------------------
// MultiLatentAttention: x@Wd -> latent; latent@W[q|kv] -> qkv (fused GEMM);
// flash attention (causal, k/v shared across 16 heads); y@Wp -> out (fp32)
// All GEMMs bf16 MFMA 16x16x32, fp32 accumulate.
// R5: flash restructured — QBLK=64/wave (256 q/block, grid 512), K/V
//     triple-buffer with counted s_waitcnt vmcnt(4) (never drains to 0),
//     one raw s_barrier per step, s_setprio around MFMA clusters.
// ---------------------------------------------------------------------------

typedef __attribute__((ext_vector_type(8))) short bf16x8;
typedef __attribute__((ext_vector_type(4))) float floatx4;

#define B_   4
#define T_   2048
#define C_   1024
#define H_   16
#define D_   64
#define L_   512
#define QKV_N 1152   // 1024 q cols + 128 kv cols

__device__ __forceinline__ float EXP2F(float x) {
    float r;
    asm("v_exp_f32 %0, %1" : "=v"(r) : "v"(x));
    return r;
}

__device__ __forceinline__ unsigned short f2bf(float f) {
    unsigned int x = __float_as_uint(f);
    unsigned int r = (x + 0x7fffu + ((x >> 16) & 1u)) >> 16;
    return (unsigned short)r;
}

// pack two fp32 -> bf16x2 (lo in low half), single instruction
__device__ __forceinline__ unsigned int cvtpk_bf(float lo, float hi) {
    unsigned int r;
    asm("v_cvt_pk_bf16_f32 %0, %1, %2" : "=v"(r) : "v"(lo), "v"(hi));
    return r;
}

// async global->LDS, 16B per lane. LDS dest = wave-uniform base + lane*16.
__device__ __forceinline__ void gload_lds16(const unsigned short* g, char* l) {
    __builtin_amdgcn_global_load_lds(
        (const __attribute__((address_space(1))) void*)g,
        (__attribute__((address_space(3))) void*)l,
        16, 0, 0);
}

// ---------------- elementwise converts ----------------
__global__ void cvt_bf16(const float* __restrict__ X, unsigned short* __restrict__ Xb, int n4) {
    int i = blockIdx.x * 256 + threadIdx.x;
    if (i >= n4) return;
    float4 v = *(const float4*)(X + (size_t)i * 4);
    ushort4 o;
    o.x = f2bf(v.x); o.y = f2bf(v.y); o.z = f2bf(v.z); o.w = f2bf(v.w);
    *(ushort4*)(Xb + (size_t)i * 4) = o;
}

// W[K][N] fp32 -> Wt[N][K] bf16 (output-coalesced), optional scale
__global__ void wtrans(const float* __restrict__ W, unsigned short* __restrict__ Wt,
                       int K, int N, float scale) {
    int idx = blockIdx.x * 256 + threadIdx.x;
    if (idx >= K * N) return;
    int n = idx / K, k = idx - n * K;
    Wt[idx] = f2bf(W[(size_t)k * N + n] * scale);
}

// qkv[B*T][1152] bf16 -> Vt[B][64][T] bf16 (v = cols 1088..1151 transposed)
__global__ void vtrans(const unsigned short* __restrict__ qkv, unsigned short* __restrict__ Vt) {
    int idx = blockIdx.x * 256 + threadIdx.x;   // B*64*T = 524288
    int t = idx & (T_ - 1);
    int d = (idx >> 11) & 63;
    int b = idx >> 17;
    Vt[idx] = qkv[((size_t)(b * T_ + t)) * QKV_N + 1024 + 64 + d];
}

// ---------------- generic bf16 GEMM: C[M][N] = A[M][K] * Bt[N][K]^T ----------------
#define BM 128
#define BN 128
#define BK 64

template <bool F32OUT>
__global__ __launch_bounds__(256) void gemm_bt(const unsigned short* __restrict__ A,
                                               const unsigned short* __restrict__ Bt,
                                               void* __restrict__ Cout,
                                               int M, int N, int K) {
    __shared__ __align__(16) char ldsA[BM * BK * 2];
    __shared__ __align__(16) char ldsB[BN * BK * 2];
    const int tid = threadIdx.x;
    const int lane = tid & 63, wave = tid >> 6;
    const int lrow = lane & 15, lhi = lane >> 4;
    const int bm = blockIdx.y * BM, bn = blockIdx.x * BN;
    const int wm = (wave >> 1) * 64, wn = (wave & 1) * 64;

    floatx4 acc[4][4] = {};

    for (int k0 = 0; k0 < K; k0 += BK) {
        // stage A/B tiles via global_load_lds; linear LDS dest, source chunk
        // pre-swizzled so LDS slot cc holds global chunk cc^(row&7).
#pragma unroll
        for (int i = 0; i < 4; ++i) {
            int c = tid + i * 256;            // 1024 chunks of 16B
            int row = c >> 3;
            int sc = ((c & 7) ^ (row & 7)) * 8;   // element offset in row
            gload_lds16(A + (size_t)(bm + row) * K + k0 + sc,
                        ldsA + (i * 256 + wave * 64) * 16);
            gload_lds16(Bt + (size_t)(bn + row) * K + k0 + sc,
                        ldsB + (i * 256 + wave * 64) * 16);
        }
        __syncthreads();
#pragma unroll
        for (int kk = 0; kk < 2; ++kk) {
            bf16x8 af[4], bfr[4];
#pragma unroll
            for (int m = 0; m < 4; ++m) {
                int row = wm + m * 16 + lrow;
                int colb = kk * 64 + lhi * 16;
                af[m] = *(const bf16x8*)(ldsA + row * 128 + (colb ^ ((row & 7) << 4)));
            }
#pragma unroll
            for (int n = 0; n < 4; ++n) {
                int row = wn + n * 16 + lrow;
                int colb = kk * 64 + lhi * 16;
                bfr[n] = *(const bf16x8*)(ldsB + row * 128 + (colb ^ ((row & 7) << 4)));
            }
#pragma unroll
            for (int m = 0; m < 4; ++m)
#pragma unroll
                for (int n = 0; n < 4; ++n)
                    acc[m][n] = __builtin_amdgcn_mfma_f32_16x16x32_bf16(af[m], bfr[n], acc[m][n], 0, 0, 0);
        }
        __syncthreads();
    }
#pragma unroll
    for (int m = 0; m < 4; ++m)
#pragma unroll
        for (int n = 0; n < 4; ++n)
#pragma unroll
            for (int r = 0; r < 4; ++r) {
                int row = bm + wm + m * 16 + lhi * 4 + r;
                int col = bn + wn + n * 16 + lrow;
                float v = acc[m][n][r];
                if (F32OUT)
                    ((float*)Cout)[(size_t)row * N + col] = v;
                else
                    ((unsigned short*)Cout)[(size_t)row * N + col] = f2bf(v);
            }
}

// ---------------- flash attention ----------------
// 512 blocks (8 q-tiles x 16 h x 4 b, heavy qt first), 256 threads (4 waves);
// wave owns 64 q rows. Swapped QK^T: S^T = K @ Q^T; q pre-scaled by
// 0.125*log2e (in Wq) so P = exp2(S); l via MFMA ones-column.
// K/V triple-buffered: issue next tile, s_waitcnt vmcnt(4) (counted, never
// 0), one s_barrier per step — prefetch stays in flight across the barrier.
__global__ __launch_bounds__(256, 2) void flash(const unsigned short* __restrict__ QKV, // [B*T][1152]
                                                const unsigned short* __restrict__ Vt,  // [B][64][T]
                                                unsigned short* __restrict__ Y) {       // [B*T][C]
    const int id = blockIdx.x;
    const int qt = 7 - (id >> 6);       // heavy tiles dispatch first
    const int h = (id >> 2) & 15;
    const int b = id & 3;
    const int tid = threadIdx.x;
    const int lane = tid & 63, wave = tid >> 6;
    const int lrow = lane & 15, lhi = lane >> 4;

    __shared__ __align__(16) char ldsK[3][64 * 128];  // [s][d0..63] swizzled
    __shared__ __align__(16) char ldsV[3][64 * 128];  // [d][s0..63] swizzled
    __shared__ __align__(16) char ldsP[4][64 * 128];  // per wave [q][s] swizzled

    const int qbase = qt * 256 + wave * 64;
    const unsigned short* KV = QKV + 1024;    // k rows, stride QKV_N
    const int nst = qt * 4 + 4;

    // per-thread staging source pointers (tile to stage next)
    const unsigned short* kp[2];
    const unsigned short* vp[2];
#pragma unroll
    for (int i = 0; i < 2; ++i) {
        int c = tid + i * 256;
        int row = c >> 3;
        int sc = ((c & 7) ^ (row & 7)) * 8;
        kp[i] = KV + ((size_t)(b * T_ + row)) * QKV_N + sc;
        vp[i] = Vt + ((size_t)(b * 64 + row)) * T_ + sc;
    }

    // Q fragments (B-operand): lane holds Q[qbase + nf*16 + lrow][kk*32 + lhi*8 + e]
    bf16x8 qf[4][2];
#pragma unroll
    for (int nf = 0; nf < 4; ++nf)
#pragma unroll
        for (int kk = 0; kk < 2; ++kk) {
            int trow = b * T_ + qbase + nf * 16 + lrow;
            int col = h * 64 + kk * 32 + lhi * 8;
            qf[nf][kk] = *(const bf16x8*)(QKV + (size_t)trow * QKV_N + col);
        }

    floatx4 o[4][4] = {};
    floatx4 ol[4] = {};   // row-sum accumulator (ones-column)

    const short one_bf = (short)0x3F80;
    const bf16x8 ones8 = {one_bf, one_bf, one_bf, one_bf, one_bf, one_bf, one_bf, one_bf};

    // prologue: stage tile 0 into buf 0; advance ptrs to tile 1
    char* kcur = ldsK[0];  char* kstg = ldsK[1];  char* kfre = ldsK[2];
    char* vcur = ldsV[0];  char* vstg = ldsV[1];  char* vfre = ldsV[2];
#pragma unroll
    for (int i = 0; i < 2; ++i) {
        gload_lds16(kp[i], kcur + (i * 256 + wave * 64) * 16);
        gload_lds16(vp[i], vcur + (i * 256 + wave * 64) * 16);
        kp[i] += 64 * QKV_N;
        vp[i] += 64;
    }

    for (int st = 0; st < nst; ++st) {
        // issue staging for tile st+1 into kstg/vstg (refetch last tile into
        // the spare buffer on the final step — keeps vmcnt count uniform)
        const bool more = (st + 1 < nst);
        const long kadj = more ? 0 : -(long)(64 * QKV_N);
        const long vadj = more ? 0 : -64L;
#pragma unroll
        for (int i = 0; i < 2; ++i) {
            gload_lds16(kp[i] + kadj, kstg + (i * 256 + wave * 64) * 16);
            gload_lds16(vp[i] + vadj, vstg + (i * 256 + wave * 64) * 16);
        }
        if (more) {
            kp[0] += 64 * QKV_N; kp[1] += 64 * QKV_N;
            vp[0] += 64;         vp[1] += 64;
        }
        // counted wait: this step's 4 loads (issued last iter) are the oldest;
        // the 4 just issued stay in flight across the barrier.
        asm volatile("s_waitcnt vmcnt(4)" ::: "memory");
        __builtin_amdgcn_s_barrier();
        __builtin_amdgcn_sched_barrier(0);

        if (st * 64 <= qbase + 63) {
            // S^T frags: row = s-local = mf*16+lhi*4+r, col = q-local = nf*16+lrow
            floatx4 s[4][4] = {};
#pragma unroll
            for (int kk = 0; kk < 2; ++kk) {
                bf16x8 kf[4];
#pragma unroll
                for (int mf = 0; mf < 4; ++mf) {
                    int row = mf * 16 + lrow;
                    int colb = kk * 64 + lhi * 16;
                    kf[mf] = *(const bf16x8*)(kcur + row * 128 + (colb ^ ((row & 7) << 4)));
                }
                __builtin_amdgcn_s_setprio(1);
#pragma unroll
                for (int mf = 0; mf < 4; ++mf)
#pragma unroll
                    for (int nf = 0; nf < 4; ++nf)
                        s[mf][nf] = __builtin_amdgcn_mfma_f32_16x16x32_bf16(kf[mf], qf[nf][kk], s[mf][nf], 0, 0, 0);
                __builtin_amdgcn_s_setprio(0);
            }

            // P = exp2(S) with causal mask (scale pre-folded into q)
#pragma unroll
            for (int nf = 0; nf < 4; ++nf) {
                if (st * 64 + 63 > qbase + nf * 16) {   // mask only near diagonal
                    int qg = qbase + nf * 16 + lrow;
#pragma unroll
                    for (int mf = 0; mf < 4; ++mf)
#pragma unroll
                        for (int r = 0; r < 4; ++r) {
                            int sg = st * 64 + mf * 16 + lhi * 4 + r;
                            if (sg > qg) s[mf][nf][r] = -1e30f;
                        }
                }
#pragma unroll
                for (int mf = 0; mf < 4; ++mf)
#pragma unroll
                    for (int rr = 0; rr < 4; ++rr)
                        s[mf][nf][rr] = EXP2F(s[mf][nf][rr]);
            }

            // write P^T -> ldsP[q][s] (cvt_pk pairs, 8B writes)
#pragma unroll
            for (int mf = 0; mf < 4; ++mf)
#pragma unroll
                for (int nf = 0; nf < 4; ++nf) {
                    uint2 pk;
                    pk.x = cvtpk_bf(s[mf][nf][0], s[mf][nf][1]);
                    pk.y = cvtpk_bf(s[mf][nf][2], s[mf][nf][3]);
                    int row = nf * 16 + lrow;
                    int colb = (mf * 16 + lhi * 4) * 2;
                    *(uint2*)(ldsP[wave] + row * 128 + (colb ^ ((row & 7) << 4))) = pk;
                }

            // PV: O[q][d] += P[q][s] * V[s][d]; l[q] += P[q][s] * 1
#pragma unroll
            for (int ss = 0; ss < 2; ++ss) {
                bf16x8 pf[4], vf[4];
#pragma unroll
                for (int m = 0; m < 4; ++m) {
                    int row = m * 16 + lrow;
                    int colb = ss * 64 + lhi * 16;
                    pf[m] = *(const bf16x8*)(ldsP[wave] + row * 128 + (colb ^ ((row & 7) << 4)));
                }
#pragma unroll
                for (int dn = 0; dn < 4; ++dn) {
                    int row = dn * 16 + lrow;
                    int colb = ss * 64 + lhi * 16;
                    vf[dn] = *(const bf16x8*)(vcur + row * 128 + (colb ^ ((row & 7) << 4)));
                }
                __builtin_amdgcn_s_setprio(1);
#pragma unroll
                for (int m = 0; m < 4; ++m) {
#pragma unroll
                    for (int dn = 0; dn < 4; ++dn)
                        o[m][dn] = __builtin_amdgcn_mfma_f32_16x16x32_bf16(pf[m], vf[dn], o[m][dn], 0, 0, 0);
                    ol[m] = __builtin_amdgcn_mfma_f32_16x16x32_bf16(pf[m], ones8, ol[m], 0, 0, 0);
                }
                __builtin_amdgcn_s_setprio(0);
            }
        }

        // rotate buffers: cur <- stg <- fre <- cur
        char* t;
        t = kcur; kcur = kstg; kstg = kfre; kfre = t;
        t = vcur; vcur = vstg; vstg = vfre; vfre = t;
    }

    // epilogue: divide by l (ol[m][rr] is l for row m*16+lhi*4+rr), store y
#pragma unroll
    for (int m = 0; m < 4; ++m) {
        float linv[4];
#pragma unroll
        for (int rr = 0; rr < 4; ++rr) linv[rr] = __builtin_amdgcn_rcpf(ol[m][rr]);
#pragma unroll
        for (int dn = 0; dn < 4; ++dn)
#pragma unroll
            for (int rr = 0; rr < 4; ++rr) {
                int trow = b * T_ + qbase + m * 16 + lhi * 4 + rr;
                int col = h * 64 + dn * 16 + lrow;
                Y[(size_t)trow * C_ + col] = f2bf(o[m][dn][rr] * linv[rr]);
            }
    }
}

// ---------------------------------------------------------------------------
extern "C" void kernel_launch(void* const* d_in, const int* in_sizes, int n_in,
                              void* d_out, int out_size, void* d_ws, size_t ws_size,
                              hipStream_t stream) {
    (void)in_sizes; (void)n_in; (void)out_size; (void)ws_size;
    const float* x   = (const float*)d_in[0];
    const float* Wd  = (const float*)d_in[1];
    const float* Wq  = (const float*)d_in[2];
    const float* Wkv = (const float*)d_in[3];
    const float* Wp  = (const float*)d_in[4];
    float* out = (float*)d_out;
    char* ws = (char*)d_ws;

    const int BT = B_ * T_;  // 8192
    const float KSC = 0.125f * 1.44269504f;   // attn scale * log2(e), folded into Wq

    unsigned short* xb     = (unsigned short*)(ws + 0);           // 16 MB (reused as y)
    unsigned short* wdT    = (unsigned short*)(ws + 16777216);    // 1 MB   [512][1024]
    unsigned short* wqkvT  = (unsigned short*)(ws + 17825792);    // 1.125 MB [1152][512]
    unsigned short* wpT    = (unsigned short*)(ws + 19005440);    // 2 MB   [1024][1024]
    unsigned short* latent = (unsigned short*)(ws + 21102592);    // 8 MB   [8192][512]
    unsigned short* qkv    = (unsigned short*)(ws + 29491200);    // 18 MB  [8192][1152]
    unsigned short* vt     = (unsigned short*)(ws + 48365568);    // 1 MB   [4][64][2048]
    unsigned short* yb     = xb;                                  // alias (x consumed by GEMM1)

    cvt_bf16<<<(BT * C_ / 4 + 255) / 256, 256, 0, stream>>>(x, xb, BT * C_ / 4);
    wtrans<<<(C_ * L_ + 255) / 256, 256, 0, stream>>>(Wd, wdT, C_, L_, 1.0f);
    wtrans<<<(L_ * C_ + 255) / 256, 256, 0, stream>>>(Wq, wqkvT, L_, C_, KSC);
    wtrans<<<(L_ * 128 + 255) / 256, 256, 0, stream>>>(Wkv, wqkvT + 1024 * 512, L_, 128, 1.0f);
    wtrans<<<(C_ * C_ + 255) / 256, 256, 0, stream>>>(Wp, wpT, C_, C_, 1.0f);

    gemm_bt<false><<<dim3(L_ / BN, BT / BM), 256, 0, stream>>>(xb, wdT, latent, BT, L_, C_);
    gemm_bt<false><<<dim3(QKV_N / BN, BT / BM), 256, 0, stream>>>(latent, wqkvT, qkv, BT, QKV_N, L_);

    vtrans<<<(B_ * 64 * T_ + 255) / 256, 256, 0, stream>>>(qkv, vt);

    flash<<<512, 256, 0, stream>>>(qkv, vt, yb);

    gemm_bt<true><<<dim3(C_ / BN, BT / BM), 256, 0, stream>>>(yb, wpT, out, BT, C_, C_);
}

// Round 8
// 145.362 us; speedup vs baseline: 1.0766x; 1.0766x over previous
//
#include <hip/hip_runtime.h>
#include <hip/hip_bf16.h>

// ---------------------------------------------------------------------------
// MultiLatentAttention: x@Wd -> latent; latent@W[q|kv] -> qkv (fused GEMM);
// flash attention (causal, k/v shared across 16 heads); y@Wp -> out (fp32)
// All GEMMs bf16 MFMA 16x16x32, fp32 accumulate.
// R6: flash — in-register P via v_cvt_pk_bf16_f32 + permlane32/16_swap
//     (no P LDS: -32KB, no LDS round-trip), QBLK=32/wave, grid 1024,
//     triple-buffered K/V (48KB) -> 3 blocks/CU. GEMMs — raw s_barrier
//     double-buffer with counted s_waitcnt vmcnt(8) (no vmcnt(0) drain).
// ---------------------------------------------------------------------------

typedef __attribute__((ext_vector_type(8))) short bf16x8;
typedef __attribute__((ext_vector_type(4))) float floatx4;
typedef __attribute__((ext_vector_type(4))) unsigned int uintx4;

#define B_   4
#define T_   2048
#define C_   1024
#define H_   16
#define D_   64
#define L_   512
#define QKV_N 1152   // 1024 q cols + 128 kv cols

__device__ __forceinline__ float EXP2F(float x) {
    float r;
    asm("v_exp_f32 %0, %1" : "=v"(r) : "v"(x));
    return r;
}

__device__ __forceinline__ unsigned short f2bf(float f) {
    unsigned int x = __float_as_uint(f);
    unsigned int r = (x + 0x7fffu + ((x >> 16) & 1u)) >> 16;
    return (unsigned short)r;
}

// pack two fp32 -> bf16x2 (lo in low half), single instruction
__device__ __forceinline__ unsigned int cvtpk_bf(float lo, float hi) {
    unsigned int r;
    asm("v_cvt_pk_bf16_f32 %0, %1, %2" : "=v"(r) : "v"(lo), "v"(hi));
    return r;
}

// D' = {D[0:31], S[0:31]}; S' = {D[32:63], S[32:63]}
__device__ __forceinline__ void pl32(unsigned int& d, unsigned int& s) {
    asm("v_permlane32_swap_b32 %0, %1" : "+v"(d), "+v"(s));
}
// D' = {D[g0], S[g0], D[g2], S[g2]}; S' = {D[g1], S[g1], D[g3], S[g3]}  (g = 16-lane row)
__device__ __forceinline__ void pl16(unsigned int& d, unsigned int& s) {
    asm("v_permlane16_swap_b32 %0, %1" : "+v"(d), "+v"(s));
}

// async global->LDS, 16B per lane. LDS dest = wave-uniform base + lane*16.
__device__ __forceinline__ void gload_lds16(const unsigned short* g, char* l) {
    __builtin_amdgcn_global_load_lds(
        (const __attribute__((address_space(1))) void*)g,
        (__attribute__((address_space(3))) void*)l,
        16, 0, 0);
}

// ---------------- elementwise converts ----------------
__global__ void cvt_bf16(const float* __restrict__ X, unsigned short* __restrict__ Xb, int n4) {
    int i = blockIdx.x * 256 + threadIdx.x;
    if (i >= n4) return;
    float4 v = *(const float4*)(X + (size_t)i * 4);
    ushort4 o;
    o.x = f2bf(v.x); o.y = f2bf(v.y); o.z = f2bf(v.z); o.w = f2bf(v.w);
    *(ushort4*)(Xb + (size_t)i * 4) = o;
}

// W[K][N] fp32 -> Wt[N][K] bf16 (output-coalesced), optional scale
__global__ void wtrans(const float* __restrict__ W, unsigned short* __restrict__ Wt,
                       int K, int N, float scale) {
    int idx = blockIdx.x * 256 + threadIdx.x;
    if (idx >= K * N) return;
    int n = idx / K, k = idx - n * K;
    Wt[idx] = f2bf(W[(size_t)k * N + n] * scale);
}

// qkv[B*T][1152] bf16 -> Vt[B][64][T] bf16 (v = cols 1088..1151 transposed)
__global__ void vtrans(const unsigned short* __restrict__ qkv, unsigned short* __restrict__ Vt) {
    int idx = blockIdx.x * 256 + threadIdx.x;   // B*64*T = 524288
    int t = idx & (T_ - 1);
    int d = (idx >> 11) & 63;
    int b = idx >> 17;
    Vt[idx] = qkv[((size_t)(b * T_ + t)) * QKV_N + 1024 + 64 + d];
}

// ---------------- generic bf16 GEMM: C[M][N] = A[M][K] * Bt[N][K]^T ----------------
#define BM 128
#define BN 128
#define BK 64

template <bool F32OUT>
__global__ __launch_bounds__(256) void gemm_bt(const unsigned short* __restrict__ A,
                                               const unsigned short* __restrict__ Bt,
                                               void* __restrict__ Cout,
                                               int M, int N, int K) {
    __shared__ __align__(16) char ldsA[2][BM * BK * 2];
    __shared__ __align__(16) char ldsB[2][BN * BK * 2];
    const int tid = threadIdx.x;
    const int lane = tid & 63, wave = tid >> 6;
    const int lrow = lane & 15, lhi = lane >> 4;
    const int bm = blockIdx.y * BM, bn = blockIdx.x * BN;
    const int wm = (wave >> 1) * 64, wn = (wave & 1) * 64;

    // per-thread staging source pointers (source chunk pre-swizzled:
    // LDS slot cc holds global chunk cc^(row&7))
    const unsigned short* ap[4];
    const unsigned short* bp[4];
#pragma unroll
    for (int i = 0; i < 4; ++i) {
        int c = tid + i * 256;            // 1024 chunks of 16B per array
        int row = c >> 3;
        int sc = ((c & 7) ^ (row & 7)) * 8;
        ap[i] = A + (size_t)(bm + row) * K + sc;
        bp[i] = Bt + (size_t)(bn + row) * K + sc;
    }
    const int nk = K >> 6;
    floatx4 acc[4][4] = {};

    // prologue: stage k-step 0 into buf 0
#pragma unroll
    for (int i = 0; i < 4; ++i) {
        gload_lds16(ap[i], ldsA[0] + (i * 256 + wave * 64) * 16);
        gload_lds16(bp[i], ldsB[0] + (i * 256 + wave * 64) * 16);
        ap[i] += BK; bp[i] += BK;
    }

    for (int t = 0; t < nk; ++t) {
        const int cur = t & 1;
        if (t + 1 < nk) {
#pragma unroll
            for (int i = 0; i < 4; ++i) {
                gload_lds16(ap[i], ldsA[cur ^ 1] + (i * 256 + wave * 64) * 16);
                gload_lds16(bp[i], ldsB[cur ^ 1] + (i * 256 + wave * 64) * 16);
                ap[i] += BK; bp[i] += BK;
            }
            // counted: wait this tile's 8 loads; next tile's 8 stay in flight
            asm volatile("s_waitcnt vmcnt(8)" ::: "memory");
        } else {
            asm volatile("s_waitcnt vmcnt(0)" ::: "memory");
        }
        __builtin_amdgcn_s_barrier();
        __builtin_amdgcn_sched_barrier(0);

#pragma unroll
        for (int kk = 0; kk < 2; ++kk) {
            bf16x8 af[4], bfr[4];
#pragma unroll
            for (int m = 0; m < 4; ++m) {
                int row = wm + m * 16 + lrow;
                int colb = kk * 64 + lhi * 16;
                af[m] = *(const bf16x8*)(ldsA[cur] + row * 128 + (colb ^ ((row & 7) << 4)));
            }
#pragma unroll
            for (int n = 0; n < 4; ++n) {
                int row = wn + n * 16 + lrow;
                int colb = kk * 64 + lhi * 16;
                bfr[n] = *(const bf16x8*)(ldsB[cur] + row * 128 + (colb ^ ((row & 7) << 4)));
            }
#pragma unroll
            for (int m = 0; m < 4; ++m)
#pragma unroll
                for (int n = 0; n < 4; ++n)
                    acc[m][n] = __builtin_amdgcn_mfma_f32_16x16x32_bf16(af[m], bfr[n], acc[m][n], 0, 0, 0);
        }
        __builtin_amdgcn_sched_barrier(0);
        __builtin_amdgcn_s_barrier();   // all reads of buf[cur] done before restage
    }
#pragma unroll
    for (int m = 0; m < 4; ++m)
#pragma unroll
        for (int n = 0; n < 4; ++n)
#pragma unroll
            for (int r = 0; r < 4; ++r) {
                int row = bm + wm + m * 16 + lhi * 4 + r;
                int col = bn + wn + n * 16 + lrow;
                float v = acc[m][n][r];
                if (F32OUT)
                    ((float*)Cout)[(size_t)row * N + col] = v;
                else
                    ((unsigned short*)Cout)[(size_t)row * N + col] = f2bf(v);
            }
}

// ---------------- flash attention ----------------
// 1024 blocks (16 q-tiles x 16 h x 4 b, heavy qt first), 256 threads;
// wave owns 32 q rows. Swapped QK^T (S^T = K@Q^T); q pre-scaled by
// 0.125*log2e so P = exp2(S); l via MFMA ones-column.
// P stays in registers: S^T frags -> PV A-frags via cvt_pk + permlane
// swaps (no P LDS). K/V triple-buffered, counted vmcnt(4), 1 barrier/step.
__global__ __launch_bounds__(256, 3) void flash(const unsigned short* __restrict__ QKV, // [B*T][1152]
                                                const unsigned short* __restrict__ Vt,  // [B][64][T]
                                                unsigned short* __restrict__ Y) {       // [B*T][C]
    const int id = blockIdx.x;
    const int qt = 15 - (id >> 6);      // heavy tiles dispatch first
    const int h = (id >> 2) & 15;
    const int b = id & 3;
    const int tid = threadIdx.x;
    const int lane = tid & 63, wave = tid >> 6;
    const int lrow = lane & 15, lhi = lane >> 4;

    __shared__ __align__(16) char ldsK[3][64 * 128];  // [s][d0..63] swizzled
    __shared__ __align__(16) char ldsV[3][64 * 128];  // [d][s0..63] swizzled

    const int qbase = qt * 128 + wave * 32;
    const unsigned short* KV = QKV + 1024;    // k rows, stride QKV_N
    const int nst = qt * 2 + 2;

    // per-thread staging source pointers (tile to stage next)
    const unsigned short* kp[2];
    const unsigned short* vp[2];
#pragma unroll
    for (int i = 0; i < 2; ++i) {
        int c = tid + i * 256;
        int row = c >> 3;
        int sc = ((c & 7) ^ (row & 7)) * 8;
        kp[i] = KV + ((size_t)(b * T_ + row)) * QKV_N + sc;
        vp[i] = Vt + ((size_t)(b * 64 + row)) * T_ + sc;
    }

    // Q fragments (B-operand): lane holds Q[qbase + nf*16 + lrow][kk*32 + lhi*8 + e]
    bf16x8 qf[2][2];
#pragma unroll
    for (int nf = 0; nf < 2; ++nf)
#pragma unroll
        for (int kk = 0; kk < 2; ++kk) {
            int trow = b * T_ + qbase + nf * 16 + lrow;
            int col = h * 64 + kk * 32 + lhi * 8;
            qf[nf][kk] = *(const bf16x8*)(QKV + (size_t)trow * QKV_N + col);
        }

    floatx4 o[2][4] = {};
    floatx4 ol[2] = {};   // row-sum accumulator (ones-column)

    const short one_bf = (short)0x3F80;
    const bf16x8 ones8 = {one_bf, one_bf, one_bf, one_bf, one_bf, one_bf, one_bf, one_bf};

    // prologue: stage tile 0 into buf 0
    char* kcur = ldsK[0];  char* kstg = ldsK[1];  char* kfre = ldsK[2];
    char* vcur = ldsV[0];  char* vstg = ldsV[1];  char* vfre = ldsV[2];
#pragma unroll
    for (int i = 0; i < 2; ++i) {
        gload_lds16(kp[i], kcur + (i * 256 + wave * 64) * 16);
        gload_lds16(vp[i], vcur + (i * 256 + wave * 64) * 16);
        kp[i] += 64 * QKV_N;
        vp[i] += 64;
    }

    for (int st = 0; st < nst; ++st) {
        // stage tile st+1 into stg (refetch last tile on final step to keep
        // the vmcnt count uniform)
        const bool more = (st + 1 < nst);
        const long kadj = more ? 0 : -(long)(64 * QKV_N);
        const long vadj = more ? 0 : -64L;
#pragma unroll
        for (int i = 0; i < 2; ++i) {
            gload_lds16(kp[i] + kadj, kstg + (i * 256 + wave * 64) * 16);
            gload_lds16(vp[i] + vadj, vstg + (i * 256 + wave * 64) * 16);
        }
        if (more) {
            kp[0] += 64 * QKV_N; kp[1] += 64 * QKV_N;
            vp[0] += 64;         vp[1] += 64;
        }
        // counted wait: this step's 4 loads (issued last iter) are the oldest
        asm volatile("s_waitcnt vmcnt(4)" ::: "memory");
        __builtin_amdgcn_s_barrier();
        __builtin_amdgcn_sched_barrier(0);

        if (st * 64 <= qbase + 31) {
            // S^T frags: row = s-local = mf*16+lhi*4+r, col = q-local = nf*16+lrow
            floatx4 s[4][2] = {};
#pragma unroll
            for (int kk = 0; kk < 2; ++kk) {
                bf16x8 kf[4];
#pragma unroll
                for (int mf = 0; mf < 4; ++mf) {
                    int row = mf * 16 + lrow;
                    int colb = kk * 64 + lhi * 16;
                    kf[mf] = *(const bf16x8*)(kcur + row * 128 + (colb ^ ((row & 7) << 4)));
                }
                __builtin_amdgcn_s_setprio(1);
#pragma unroll
                for (int mf = 0; mf < 4; ++mf)
#pragma unroll
                    for (int nf = 0; nf < 2; ++nf)
                        s[mf][nf] = __builtin_amdgcn_mfma_f32_16x16x32_bf16(kf[mf], qf[nf][kk], s[mf][nf], 0, 0, 0);
                __builtin_amdgcn_s_setprio(0);
            }

            // causal mask + P = exp2(S) (scale pre-folded into q)
#pragma unroll
            for (int nf = 0; nf < 2; ++nf) {
                if (st * 64 + 63 > qbase + nf * 16) {   // mask only near diagonal
                    int qg = qbase + nf * 16 + lrow;
#pragma unroll
                    for (int mf = 0; mf < 4; ++mf)
#pragma unroll
                        for (int r = 0; r < 4; ++r) {
                            int sg = st * 64 + mf * 16 + lhi * 4 + r;
                            if (sg > qg) s[mf][nf][r] = -1e30f;
                        }
                }
#pragma unroll
                for (int mf = 0; mf < 4; ++mf)
#pragma unroll
                    for (int rr = 0; rr < 4; ++rr)
                        s[mf][nf][rr] = EXP2F(s[mf][nf][rr]);
            }

            // in-register P^T -> PV A-fragment transform:
            // word j at lane (lrow,khi) = cvt_pk of s[2ss+(khi>>1)][nf] regs
            // {2(j&1), +1} taken from source 16-row (khi&1)*2 + (j>>1).
            // (w0,w2) = pl16(pl32(A0,B0)); (w1,w3) = pl16(pl32(A1,B1)).
            bf16x8 pfr[2][2];
#pragma unroll
            for (int nf = 0; nf < 2; ++nf)
#pragma unroll
                for (int ss = 0; ss < 2; ++ss) {
                    unsigned int A0 = cvtpk_bf(s[2 * ss][nf][0], s[2 * ss][nf][1]);
                    unsigned int A1 = cvtpk_bf(s[2 * ss][nf][2], s[2 * ss][nf][3]);
                    unsigned int B0 = cvtpk_bf(s[2 * ss + 1][nf][0], s[2 * ss + 1][nf][1]);
                    unsigned int B1 = cvtpk_bf(s[2 * ss + 1][nf][2], s[2 * ss + 1][nf][3]);
                    pl32(A0, B0); pl16(A0, B0);   // A0=word0, B0=word2
                    pl32(A1, B1); pl16(A1, B1);   // A1=word1, B1=word3
                    uintx4 pw; pw.x = A0; pw.y = A1; pw.z = B0; pw.w = B1;
                    pfr[nf][ss] = __builtin_bit_cast(bf16x8, pw);
                }

            // PV: O[q][d] += P[q][s] * V[s][d]; l[q] += P[q][s] * 1
#pragma unroll
            for (int ss = 0; ss < 2; ++ss) {
                bf16x8 vf[4];
#pragma unroll
                for (int dn = 0; dn < 4; ++dn) {
                    int row = dn * 16 + lrow;
                    int colb = ss * 64 + lhi * 16;
                    vf[dn] = *(const bf16x8*)(vcur + row * 128 + (colb ^ ((row & 7) << 4)));
                }
                __builtin_amdgcn_s_setprio(1);
#pragma unroll
                for (int m = 0; m < 2; ++m) {
#pragma unroll
                    for (int dn = 0; dn < 4; ++dn)
                        o[m][dn] = __builtin_amdgcn_mfma_f32_16x16x32_bf16(pfr[m][ss], vf[dn], o[m][dn], 0, 0, 0);
                    ol[m] = __builtin_amdgcn_mfma_f32_16x16x32_bf16(pfr[m][ss], ones8, ol[m], 0, 0, 0);
                }
                __builtin_amdgcn_s_setprio(0);
            }
        }

        // rotate buffers: cur <- stg <- fre <- cur
        char* t;
        t = kcur; kcur = kstg; kstg = kfre; kfre = t;
        t = vcur; vcur = vstg; vstg = vfre; vfre = t;
    }

    // epilogue: divide by l (ol[m][rr] is l for row m*16+lhi*4+rr), store y
#pragma unroll
    for (int m = 0; m < 2; ++m) {
        float linv[4];
#pragma unroll
        for (int rr = 0; rr < 4; ++rr) linv[rr] = __builtin_amdgcn_rcpf(ol[m][rr]);
#pragma unroll
        for (int dn = 0; dn < 4; ++dn)
#pragma unroll
            for (int rr = 0; rr < 4; ++rr) {
                int trow = b * T_ + qbase + m * 16 + lhi * 4 + rr;
                int col = h * 64 + dn * 16 + lrow;
                Y[(size_t)trow * C_ + col] = f2bf(o[m][dn][rr] * linv[rr]);
            }
    }
}

// ---------------------------------------------------------------------------
extern "C" void kernel_launch(void* const* d_in, const int* in_sizes, int n_in,
                              void* d_out, int out_size, void* d_ws, size_t ws_size,
                              hipStream_t stream) {
    (void)in_sizes; (void)n_in; (void)out_size; (void)ws_size;
    const float* x   = (const float*)d_in[0];
    const float* Wd  = (const float*)d_in[1];
    const float* Wq  = (const float*)d_in[2];
    const float* Wkv = (const float*)d_in[3];
    const float* Wp  = (const float*)d_in[4];
    float* out = (float*)d_out;
    char* ws = (char*)d_ws;

    const int BT = B_ * T_;  // 8192
    const float KSC = 0.125f * 1.44269504f;   // attn scale * log2(e), folded into Wq

    unsigned short* xb     = (unsigned short*)(ws + 0);           // 16 MB (reused as y)
    unsigned short* wdT    = (unsigned short*)(ws + 16777216);    // 1 MB   [512][1024]
    unsigned short* wqkvT  = (unsigned short*)(ws + 17825792);    // 1.125 MB [1152][512]
    unsigned short* wpT    = (unsigned short*)(ws + 19005440);    // 2 MB   [1024][1024]
    unsigned short* latent = (unsigned short*)(ws + 21102592);    // 8 MB   [8192][512]
    unsigned short* qkv    = (unsigned short*)(ws + 29491200);    // 18 MB  [8192][1152]
    unsigned short* vt     = (unsigned short*)(ws + 48365568);    // 1 MB   [4][64][2048]
    unsigned short* yb     = xb;                                  // alias (x consumed by GEMM1)

    cvt_bf16<<<(BT * C_ / 4 + 255) / 256, 256, 0, stream>>>(x, xb, BT * C_ / 4);
    wtrans<<<(C_ * L_ + 255) / 256, 256, 0, stream>>>(Wd, wdT, C_, L_, 1.0f);
    wtrans<<<(L_ * C_ + 255) / 256, 256, 0, stream>>>(Wq, wqkvT, L_, C_, KSC);
    wtrans<<<(L_ * 128 + 255) / 256, 256, 0, stream>>>(Wkv, wqkvT + 1024 * 512, L_, 128, 1.0f);
    wtrans<<<(C_ * C_ + 255) / 256, 256, 0, stream>>>(Wp, wpT, C_, C_, 1.0f);

    gemm_bt<false><<<dim3(L_ / BN, BT / BM), 256, 0, stream>>>(xb, wdT, latent, BT, L_, C_);
    gemm_bt<false><<<dim3(QKV_N / BN, BT / BM), 256, 0, stream>>>(latent, wqkvT, qkv, BT, QKV_N, L_);

    vtrans<<<(B_ * 64 * T_ + 255) / 256, 256, 0, stream>>>(qkv, vt);

    flash<<<1024, 256, 0, stream>>>(qkv, vt, yb);

    gemm_bt<true><<<dim3(C_ / BN, BT / BM), 256, 0, stream>>>(yb, wpT, out, BT, C_, C_);
}